// Round 3
// baseline (15578.015 us; speedup 1.0000x reference)
//
#include <hip/hip_runtime.h>
#include <math.h>

#define BSZ 512
#define TT  100
#define NDD 10
#define DSS 6
#define INS 256
#define HID 256
#define CAT 2816   // INS*NDD + HID
#define KZ  320    // 64 (desc: 60 + 4 pad) + 256 (h)
#define NOUTP 320  // padded output rows: 256 (W2) + 10 (Wv) + 54 zero
#define NOUT 266
#define NBLK 256
#define NTHR 1024

typedef short sh8 __attribute__((ext_vector_type(8)));
typedef float f4  __attribute__((ext_vector_type(4)));
typedef unsigned short ushort_t;

__device__ __forceinline__ float sigf(float x) { return 1.0f / (1.0f + expf(-x)); }

__device__ __forceinline__ ushort_t f2bf(float f) {
    union { float f; unsigned int u; } v; v.f = f;
    unsigned int r = (v.u + 0x7FFFu + ((v.u >> 16) & 1u)) >> 16;
    return (ushort_t)r;
}

#define MFMA(a, b, c) __builtin_amdgcn_mfma_f32_16x16x32_bf16((a), (b), (c), 0, 0, 0)

// ---------------------------------------------------------------------------
// Precompute kernels (unchanged from validated round-2 versions)
// ---------------------------------------------------------------------------
__global__ __launch_bounds__(64) void k_fold(
    const float* __restrict__ W1, const float* __restrict__ Wd,
    const float* __restrict__ bd, const float* __restrict__ b1,
    ushort_t* __restrict__ Wzc, float* __restrict__ bfold)
{
    __shared__ float sW1[2560];
    __shared__ float sWd[INS * DSS];
    __shared__ float red[64];
    const int j = blockIdx.x;
    const int tid = threadIdx.x;
    for (int f = tid; f < INS * DSS; f += 64) sWd[f] = Wd[f];
    for (int f = tid; f < 2560; f += 64) sW1[f] = W1[(size_t)j * CAT + f];
    __syncthreads();
    if (tid < 60) {
        int n = tid / DSS, d = tid - n * DSS;
        float acc = 0.f;
        for (int i = 0; i < INS; ++i) acc += sW1[n * INS + i] * sWd[i * DSS + d];
        Wzc[j * KZ + tid] = f2bf(acc);
    } else {
        Wzc[j * KZ + tid] = 0;
    }
    for (int q = tid; q < HID; q += 64)
        Wzc[j * KZ + 64 + q] = f2bf(W1[(size_t)j * CAT + 2560 + q]);
    float acc = 0.f;
    for (int p = tid; p < 2560; p += 64) acc += sW1[p] * bd[p & (INS - 1)];
    red[tid] = acc;
    __syncthreads();
    for (int s = 32; s > 0; s >>= 1) {
        if (tid < s) red[tid] += red[tid + s];
        __syncthreads();
    }
    if (tid == 0) bfold[j] = b1[j] + red[0];
}

__global__ __launch_bounds__(256) void k_dfold(
    const float* __restrict__ desc, ushort_t* __restrict__ Dfold)
{
    int idx = blockIdx.x * 256 + threadIdx.x;
    int p = idx & 63;
    int tb = idx >> 6;
    int t = tb / BSZ;
    int b = tb - t * BSZ;
    float v = (p < 60) ? desc[(size_t)b * (TT * 60) + t * 60 + p] : 0.f;
    Dfold[idx] = f2bf(v);
}

__global__ __launch_bounds__(256) void k_prep_g(
    const float* __restrict__ Wih, const float* __restrict__ Whh,
    const float* __restrict__ bih, const float* __restrict__ bhh,
    ushort_t* __restrict__ Wg, float* __restrict__ bg)
{
    int idx = blockIdx.x * 256 + threadIdx.x;   // 1024*512
    int newr = idx >> 9, k = idx & 511;
    int j = newr >> 2, g = newr & 3;
    int src_row = g * 256 + j;
    float v = (k < 256) ? Wih[(size_t)src_row * INS + k]
                        : Whh[(size_t)src_row * HID + (k - 256)];
    Wg[idx] = f2bf(v);
    if (k == 0) bg[newr] = bih[src_row] + bhh[src_row];
}

__global__ __launch_bounds__(256) void k_prep_o(
    const float* __restrict__ W2, const float* __restrict__ Wv,
    ushort_t* __restrict__ Wout)
{
    int idx = blockIdx.x * 256 + threadIdx.x;   // 320*2816
    int r = idx / CAT, k = idx - r * CAT;
    float v = 0.f;
    if (r < 256) v = W2[(size_t)r * CAT + k];
    else if (r < NOUT) v = Wv[(size_t)(r - 256) * CAT + k];
    Wout[idx] = f2bf(v);
}

// ---------------------------------------------------------------------------
// Grid barrier: one fresh counter per crossing (zeroed in-graph each launch).
// Device(agent)-scope atomics provide cross-XCD release/acquire.
// ---------------------------------------------------------------------------
__device__ __forceinline__ void gridbar(unsigned int* bars, int idx) {
    __syncthreads();   // drains vmcnt: block's global stores are complete
    if (threadIdx.x == 0) {
        unsigned int* p = bars + idx;
        __hip_atomic_fetch_add(p, 1u, __ATOMIC_ACQ_REL, __HIP_MEMORY_SCOPE_AGENT);
        while (__hip_atomic_load(p, __ATOMIC_ACQUIRE, __HIP_MEMORY_SCOPE_AGENT)
               < (unsigned int)NBLK) {
            __builtin_amdgcn_s_sleep(1);
        }
    }
    __syncthreads();
}

// ---------------------------------------------------------------------------
// Persistent kernel: 256 blocks x 1024 threads, 100 steps, 3 barriers/step.
// Phase G : gates GEMM (M512,N1024,K512) + LSTM cell -> h into xh_nxt[.,256:512]
// Phase Z : z = relu([Dfold_t | h] @ Wzc.T + bfold)  (M512,N2816,K320)
// Phase OF: {inp, out} = z @ Wout.T (block-internal split-K over 16 waves)
//           relu->xh_nxt[.,0:256], sigmoid->out
// ---------------------------------------------------------------------------
__global__ void __launch_bounds__(NTHR, 4) k_persist(
    const ushort_t* __restrict__ Wg, const float* __restrict__ bg,
    const ushort_t* __restrict__ Wzc, const float* __restrict__ bfold,
    const ushort_t* __restrict__ Wout, const float* __restrict__ b2,
    const float* __restrict__ bv, const ushort_t* __restrict__ Dfold,
    ushort_t* __restrict__ xhA, ushort_t* __restrict__ xhB,
    float* __restrict__ c, ushort_t* __restrict__ z,
    float* __restrict__ out, unsigned int* __restrict__ bars)
{
    __shared__ float red[8][32][33];                       // 33.8 KB (OF reduce)
    float (*sg)[16][17] = (float(*)[16][17])&red[0][0][0]; // aliased for G

    const int bid = blockIdx.x;
    const int tid = threadIdx.x;
    const int w = tid >> 6, l = tid & 63, quad = l >> 4, lr = l & 15;

    int bar = 0;
    for (int t = 0; t < TT; ++t) {
        const ushort_t* xh = (t & 1) ? xhB : xhA;
        ushort_t*       xn = (t & 1) ? xhA : xhB;
        const ushort_t* Dt = Dfold + (size_t)t * BSZ * 64;

        // ================= Phase G: gates + cell =================
        {
            const int n_grp = bid & 7, m_t = bid >> 3;     // XCD-aligned N slice
            const int slot = w >> 1, kh = w & 1;
            const int n_t = n_grp * 8 + slot;
            const int m0 = m_t * 16, n0 = n_t * 16;
            f4 acc = {};
            const ushort_t* arow = xh + (size_t)(m0 + lr) * 512 + kh * 256 + quad * 8;
            const ushort_t* brow = Wg + (size_t)(n0 + lr) * 512 + kh * 256 + quad * 8;
            #pragma unroll
            for (int ks = 0; ks < 8; ++ks) {
                sh8 a = *(const sh8*)(arow + ks * 32);
                sh8 b = *(const sh8*)(brow + ks * 32);
                acc = MFMA(a, b, acc);
            }
            if (kh == 0) {
                #pragma unroll
                for (int r = 0; r < 4; ++r) sg[slot][quad * 4 + r][lr] = acc[r];
            }
            __syncthreads();
            if (kh == 1) {
                #pragma unroll
                for (int r = 0; r < 4; ++r) sg[slot][quad * 4 + r][lr] += acc[r];
            }
            __syncthreads();
            if (tid < 512) {
                int slot2 = tid >> 6, r = (tid >> 2) & 15, jl = tid & 3;
                int nt2 = n_grp * 8 + slot2;
                int brow2 = m0 + r;
                int j = nt2 * 4 + jl;
                float ai = sg[slot2][r][4 * jl + 0] + bg[nt2 * 16 + 4 * jl + 0];
                float af = sg[slot2][r][4 * jl + 1] + bg[nt2 * 16 + 4 * jl + 1];
                float ag = sg[slot2][r][4 * jl + 2] + bg[nt2 * 16 + 4 * jl + 2];
                float ao = sg[slot2][r][4 * jl + 3] + bg[nt2 * 16 + 4 * jl + 3];
                int ci = brow2 * 256 + j;
                float cc = sigf(af) * c[ci] + sigf(ai) * tanhf(ag);
                c[ci] = cc;
                float hh = sigf(ao) * tanhf(cc);
                xn[(size_t)brow2 * 512 + 256 + j] = f2bf(hh);
            }
        }
        gridbar(bars, bar++);

        // ================= Phase Z: z GEMM =================
        {
            const int x = bid & 7, cid = bid >> 3;         // XCD-aligned N slice
            #pragma unroll
            for (int rep = 0; rep < 2; ++rep) {
                int u = cid * 16 + w + rep * 512;
                if (u < 704) {                             // 32 m-tiles x 22 n-tiles
                    int m_t = u / 22, nl = u - m_t * 22;
                    int n_t = x * 22 + nl;
                    int m0 = m_t * 16, n0 = n_t * 16;
                    f4 acc = {};
                    const ushort_t* brow = Wzc + (size_t)(n0 + lr) * KZ + quad * 8;
                    const ushort_t* drow = Dt + (size_t)(m0 + lr) * 64 + quad * 8;
                    #pragma unroll
                    for (int ks = 0; ks < 2; ++ks) {       // k 0..63: descriptors
                        sh8 a = *(const sh8*)(drow + ks * 32);
                        sh8 b = *(const sh8*)(brow + ks * 32);
                        acc = MFMA(a, b, acc);
                    }
                    const ushort_t* hrow = xn + (size_t)(m0 + lr) * 512 + 256 + quad * 8;
                    #pragma unroll
                    for (int ks = 0; ks < 8; ++ks) {       // k 64..319: h
                        sh8 a = *(const sh8*)(hrow + ks * 32);
                        sh8 b = *(const sh8*)(brow + 64 + ks * 32);
                        acc = MFMA(a, b, acc);
                    }
                    float bia = bfold[n0 + lr];
                    #pragma unroll
                    for (int r = 0; r < 4; ++r) {
                        float v = fmaxf(acc[r] + bia, 0.f);
                        z[(size_t)(m0 + quad * 4 + r) * CAT + n0 + lr] = f2bf(v);
                    }
                }
            }
        }
        gridbar(bars, bar++);

        // ================= Phase OF: out GEMM + fin =================
        {
            int m_t = -1, n_t = 0;
            if (bid < 128)      { m_t = bid >> 3; n_t = bid & 7; }
            else if (bid < 160) { int q = bid - 128; m_t = q >> 1; n_t = 8 + (q & 1); }
            if (m_t >= 0) {
                const int m0 = m_t * 32, n0 = n_t * 32;
                int k0, nk;
                if (w < 8) { k0 = w * 192; nk = 6; }                 // 8*192
                else       { k0 = 1536 + (w - 8) * 160; nk = 5; }    // + 8*160 = 2816
                f4 acc[2][2] = {};
                const ushort_t* za = z + (size_t)(m0 + lr) * CAT + k0 + quad * 8;
                const ushort_t* wb = Wout + (size_t)(n0 + lr) * CAT + k0 + quad * 8;
                for (int ks = 0; ks < nk; ++ks) {
                    sh8 a0 = *(const sh8*)(za + ks * 32);
                    sh8 a1 = *(const sh8*)(za + (size_t)16 * CAT + ks * 32);
                    sh8 b0 = *(const sh8*)(wb + ks * 32);
                    sh8 b1 = *(const sh8*)(wb + (size_t)16 * CAT + ks * 32);
                    acc[0][0] = MFMA(a0, b0, acc[0][0]);
                    acc[0][1] = MFMA(a0, b1, acc[0][1]);
                    acc[1][0] = MFMA(a1, b0, acc[1][0]);
                    acc[1][1] = MFMA(a1, b1, acc[1][1]);
                }
                if (w >= 8) {
                    #pragma unroll
                    for (int i = 0; i < 2; ++i)
                        #pragma unroll
                        for (int j2 = 0; j2 < 2; ++j2)
                            #pragma unroll
                            for (int r = 0; r < 4; ++r)
                                red[w - 8][i * 16 + quad * 4 + r][j2 * 16 + lr] = acc[i][j2][r];
                }
                __syncthreads();
                if (w < 8) {
                    #pragma unroll
                    for (int i = 0; i < 2; ++i)
                        #pragma unroll
                        for (int j2 = 0; j2 < 2; ++j2)
                            #pragma unroll
                            for (int r = 0; r < 4; ++r) {
                                float v = acc[i][j2][r] +
                                    red[w][i * 16 + quad * 4 + r][j2 * 16 + lr];
                                red[w][i * 16 + quad * 4 + r][j2 * 16 + lr] = v;
                            }
                }
                __syncthreads();
                {
                    int mloc = tid >> 5, nloc = tid & 31;
                    float s = 0.f;
                    #pragma unroll
                    for (int sI = 0; sI < 8; ++sI) s += red[sI][mloc][nloc];
                    int r = n0 + nloc, b = m0 + mloc;
                    if (r < 256) {
                        xn[(size_t)b * 512 + r] = f2bf(fmaxf(s + b2[r], 0.f));
                    } else if (r < NOUT) {
                        out[(size_t)b * (TT * NDD) + t * NDD + (r - 256)] = sigf(s + bv[r - 256]);
                    }
                }
            }
        }
        gridbar(bars, bar++);
    }
}

// ---------------------------------------------------------------------------
extern "C" void kernel_launch(void* const* d_in, const int* in_sizes, int n_in,
                              void* d_out, int out_size, void* d_ws, size_t ws_size,
                              hipStream_t stream)
{
    const float* desc = (const float*)d_in[0];
    const float* Wd   = (const float*)d_in[1];
    const float* bd   = (const float*)d_in[2];
    const float* W1   = (const float*)d_in[3];
    const float* b1   = (const float*)d_in[4];
    const float* W2   = (const float*)d_in[5];
    const float* b2   = (const float*)d_in[6];
    const float* Wv   = (const float*)d_in[7];
    const float* bv   = (const float*)d_in[8];
    const float* Wih  = (const float*)d_in[9];
    const float* Whh  = (const float*)d_in[10];
    const float* bih  = (const float*)d_in[11];
    const float* bhh  = (const float*)d_in[12];
    float* out = (float*)d_out;

    char* base = (char*)d_ws;
    size_t off = 0;
    auto alloc = [&](size_t bytes) -> char* {
        char* p = base + off;
        off = (off + bytes + 255) & ~(size_t)255;
        return p;
    };
    float*        c_    = (float*)alloc(BSZ * HID * 4);
    ushort_t*     xhA   = (ushort_t*)alloc(BSZ * 512 * 2);
    ushort_t*     xhB   = (ushort_t*)alloc(BSZ * 512 * 2);
    ushort_t*     z     = (ushort_t*)alloc((size_t)BSZ * CAT * 2);
    ushort_t*     Wzc   = (ushort_t*)alloc((size_t)CAT * KZ * 2);
    float*        bfold = (float*)alloc(CAT * 4);
    ushort_t*     Wg    = (ushort_t*)alloc(1024 * 512 * 2);
    float*        bg    = (float*)alloc(1024 * 4);
    ushort_t*     Wout  = (ushort_t*)alloc((size_t)NOUTP * CAT * 2);
    ushort_t*     Dfold = (ushort_t*)alloc((size_t)TT * BSZ * 64 * 2);
    unsigned int* bars  = (unsigned int*)alloc((TT * 3 + 4) * 4);

    hipMemsetAsync(c_,   0, BSZ * HID * 4, stream);
    hipMemsetAsync(xhA,  0, BSZ * 512 * 2, stream);
    hipMemsetAsync(bars, 0, (TT * 3 + 4) * 4, stream);

    k_fold  <<<CAT, 64, 0, stream>>>(W1, Wd, bd, b1, Wzc, bfold);
    k_dfold <<<(TT * BSZ * 64) / 256, 256, 0, stream>>>(desc, Dfold);
    k_prep_g<<<(1024 * 512) / 256, 256, 0, stream>>>(Wih, Whh, bih, bhh, Wg, bg);
    k_prep_o<<<(NOUTP * CAT) / 256, 256, 0, stream>>>(W2, Wv, Wout);

    void* args[] = {
        (void*)&Wg, (void*)&bg, (void*)&Wzc, (void*)&bfold, (void*)&Wout,
        (void*)&b2, (void*)&bv, (void*)&Dfold, (void*)&xhA, (void*)&xhB,
        (void*)&c_, (void*)&z, (void*)&out, (void*)&bars
    };
    hipLaunchCooperativeKernel((const void*)k_persist, dim3(NBLK), dim3(NTHR),
                               args, 0, stream);
}

// Round 4
// 9261.954 us; speedup vs baseline: 1.6819x; 1.6819x over previous
//
#include <hip/hip_runtime.h>
#include <math.h>

#define BSZ 512
#define TT  100
#define NDD 10
#define DSS 6
#define INS 256
#define HID 256
#define CAT 2816   // INS*NDD + HID
#define KZ  320    // 64 (desc: 60 + 4 pad) + 256 (h)
#define NOUTP 320  // padded output rows: 256 (W2) + 10 (Wv) + 54 zero
#define NOUT 266
#define NBLK 256
#define NTHR 1024

typedef short sh8 __attribute__((ext_vector_type(8)));
typedef float f4  __attribute__((ext_vector_type(4)));
typedef unsigned short ushort_t;

__device__ __forceinline__ float sigf(float x) { return 1.0f / (1.0f + expf(-x)); }

__device__ __forceinline__ ushort_t f2bf(float f) {
    union { float f; unsigned int u; } v; v.f = f;
    unsigned int r = (v.u + 0x7FFFu + ((v.u >> 16) & 1u)) >> 16;
    return (ushort_t)r;
}

#define MFMA(a, b, c) __builtin_amdgcn_mfma_f32_16x16x32_bf16((a), (b), (c), 0, 0, 0)

// ---------------------------------------------------------------------------
// Precompute kernels (unchanged, validated)
// ---------------------------------------------------------------------------
__global__ __launch_bounds__(64) void k_fold(
    const float* __restrict__ W1, const float* __restrict__ Wd,
    const float* __restrict__ bd, const float* __restrict__ b1,
    ushort_t* __restrict__ Wzc, float* __restrict__ bfold)
{
    __shared__ float sW1[2560];
    __shared__ float sWd[INS * DSS];
    __shared__ float red[64];
    const int j = blockIdx.x;
    const int tid = threadIdx.x;
    for (int f = tid; f < INS * DSS; f += 64) sWd[f] = Wd[f];
    for (int f = tid; f < 2560; f += 64) sW1[f] = W1[(size_t)j * CAT + f];
    __syncthreads();
    if (tid < 60) {
        int n = tid / DSS, d = tid - n * DSS;
        float acc = 0.f;
        for (int i = 0; i < INS; ++i) acc += sW1[n * INS + i] * sWd[i * DSS + d];
        Wzc[j * KZ + tid] = f2bf(acc);
    } else {
        Wzc[j * KZ + tid] = 0;
    }
    for (int q = tid; q < HID; q += 64)
        Wzc[j * KZ + 64 + q] = f2bf(W1[(size_t)j * CAT + 2560 + q]);
    float acc = 0.f;
    for (int p = tid; p < 2560; p += 64) acc += sW1[p] * bd[p & (INS - 1)];
    red[tid] = acc;
    __syncthreads();
    for (int s = 32; s > 0; s >>= 1) {
        if (tid < s) red[tid] += red[tid + s];
        __syncthreads();
    }
    if (tid == 0) bfold[j] = b1[j] + red[0];
}

__global__ __launch_bounds__(256) void k_dfold(
    const float* __restrict__ desc, ushort_t* __restrict__ Dfold)
{
    int idx = blockIdx.x * 256 + threadIdx.x;
    int p = idx & 63;
    int tb = idx >> 6;
    int t = tb / BSZ;
    int b = tb - t * BSZ;
    float v = (p < 60) ? desc[(size_t)b * (TT * 60) + t * 60 + p] : 0.f;
    Dfold[idx] = f2bf(v);
}

__global__ __launch_bounds__(256) void k_prep_g(
    const float* __restrict__ Wih, const float* __restrict__ Whh,
    const float* __restrict__ bih, const float* __restrict__ bhh,
    ushort_t* __restrict__ Wg, float* __restrict__ bg)
{
    int idx = blockIdx.x * 256 + threadIdx.x;   // 1024*512
    int newr = idx >> 9, k = idx & 511;
    int j = newr >> 2, g = newr & 3;
    int src_row = g * 256 + j;
    float v = (k < 256) ? Wih[(size_t)src_row * INS + k]
                        : Whh[(size_t)src_row * HID + (k - 256)];
    Wg[idx] = f2bf(v);
    if (k == 0) bg[newr] = bih[src_row] + bhh[src_row];
}

__global__ __launch_bounds__(256) void k_prep_o(
    const float* __restrict__ W2, const float* __restrict__ Wv,
    ushort_t* __restrict__ Wout)
{
    int idx = blockIdx.x * 256 + threadIdx.x;   // 320*2816
    int r = idx / CAT, k = idx - r * CAT;
    float v = 0.f;
    if (r < 256) v = W2[(size_t)r * CAT + k];
    else if (r < NOUT) v = Wv[(size_t)(r - 256) * CAT + k];
    Wout[idx] = f2bf(v);
}

// ---------------------------------------------------------------------------
// Grid barrier, contention-safe version:
//  - arrive: fetch_add RELEASE (one L2 writeback per block — needed so this
//    block's global stores become visible device-wide)
//  - spin:   RELAXED agent loads (read through to LLC, NO cache invalidation)
//  - exit:   one ACQUIRE load (one L2/L1 invalidate per block per barrier)
// Round-3 bug: ACQUIRE load in the spin loop emitted buffer_inv per poll,
// thrashing all 8 L2s continuously (FETCH_SIZE 1.4 GB, 50 us/barrier).
// ---------------------------------------------------------------------------
__device__ __forceinline__ void gridbar(unsigned int* bars, int idx) {
    __syncthreads();   // all waves' stores issued & drained (vmcnt)
    if (threadIdx.x == 0) {
        unsigned int* p = bars + idx;
        __hip_atomic_fetch_add(p, 1u, __ATOMIC_RELEASE, __HIP_MEMORY_SCOPE_AGENT);
        while (__hip_atomic_load(p, __ATOMIC_RELAXED, __HIP_MEMORY_SCOPE_AGENT)
               < (unsigned int)NBLK) {
            __builtin_amdgcn_s_sleep(4);
        }
        (void)__hip_atomic_load(p, __ATOMIC_ACQUIRE, __HIP_MEMORY_SCOPE_AGENT);
    }
    __syncthreads();
}

// ---------------------------------------------------------------------------
// Persistent kernel: 256 blocks x 1024 threads, 100 steps, 3 barriers/step.
// Phase G : gates GEMM (M512,N1024,K512) + LSTM cell -> h into xh_nxt[.,256:512]
// Phase Z : z = relu([Dfold_t | h] @ Wzc.T + bfold)  (M512,N2816,K320)
// Phase OF: {inp, out} = z @ Wout.T (block-internal split-K over 16 waves)
//           relu->xh_nxt[.,0:256], sigmoid->out
// ---------------------------------------------------------------------------
__global__ void __launch_bounds__(NTHR, 4) k_persist(
    const ushort_t* __restrict__ Wg, const float* __restrict__ bg,
    const ushort_t* __restrict__ Wzc, const float* __restrict__ bfold,
    const ushort_t* __restrict__ Wout, const float* __restrict__ b2,
    const float* __restrict__ bv, const ushort_t* __restrict__ Dfold,
    ushort_t* __restrict__ xhA, ushort_t* __restrict__ xhB,
    float* __restrict__ c, ushort_t* __restrict__ z,
    float* __restrict__ out, unsigned int* __restrict__ bars)
{
    __shared__ float red[8][32][33];                       // 33.8 KB (OF reduce)
    float (*sg)[16][17] = (float(*)[16][17])&red[0][0][0]; // aliased for G

    const int bid = blockIdx.x;
    const int tid = threadIdx.x;
    const int w = tid >> 6, l = tid & 63, quad = l >> 4, lr = l & 15;

    int bar = 0;
    for (int t = 0; t < TT; ++t) {
        const ushort_t* xh = (t & 1) ? xhB : xhA;
        ushort_t*       xn = (t & 1) ? xhA : xhB;
        const ushort_t* Dt = Dfold + (size_t)t * BSZ * 64;

        // ================= Phase G: gates + cell =================
        {
            const int n_grp = bid & 7, m_t = bid >> 3;     // XCD-aligned N slice
            const int slot = w >> 1, kh = w & 1;
            const int n_t = n_grp * 8 + slot;
            const int m0 = m_t * 16, n0 = n_t * 16;
            f4 acc = {};
            const ushort_t* arow = xh + (size_t)(m0 + lr) * 512 + kh * 256 + quad * 8;
            const ushort_t* brow = Wg + (size_t)(n0 + lr) * 512 + kh * 256 + quad * 8;
            #pragma unroll
            for (int ks = 0; ks < 8; ++ks) {
                sh8 a = *(const sh8*)(arow + ks * 32);
                sh8 b = *(const sh8*)(brow + ks * 32);
                acc = MFMA(a, b, acc);
            }
            if (kh == 0) {
                #pragma unroll
                for (int r = 0; r < 4; ++r) sg[slot][quad * 4 + r][lr] = acc[r];
            }
            __syncthreads();
            if (kh == 1) {
                #pragma unroll
                for (int r = 0; r < 4; ++r) sg[slot][quad * 4 + r][lr] += acc[r];
            }
            __syncthreads();
            if (tid < 512) {
                int slot2 = tid >> 6, r = (tid >> 2) & 15, jl = tid & 3;
                int nt2 = n_grp * 8 + slot2;
                int brow2 = m0 + r;
                int j = nt2 * 4 + jl;
                float ai = sg[slot2][r][4 * jl + 0] + bg[nt2 * 16 + 4 * jl + 0];
                float af = sg[slot2][r][4 * jl + 1] + bg[nt2 * 16 + 4 * jl + 1];
                float ag = sg[slot2][r][4 * jl + 2] + bg[nt2 * 16 + 4 * jl + 2];
                float ao = sg[slot2][r][4 * jl + 3] + bg[nt2 * 16 + 4 * jl + 3];
                int ci = brow2 * 256 + j;
                float cc = sigf(af) * c[ci] + sigf(ai) * tanhf(ag);
                c[ci] = cc;
                float hh = sigf(ao) * tanhf(cc);
                xn[(size_t)brow2 * 512 + 256 + j] = f2bf(hh);
            }
        }
        gridbar(bars, bar++);

        // ================= Phase Z: z GEMM =================
        {
            const int x = bid & 7, cid = bid >> 3;         // XCD-aligned N slice
            #pragma unroll
            for (int rep = 0; rep < 2; ++rep) {
                int u = cid * 16 + w + rep * 512;
                if (u < 704) {                             // 32 m-tiles x 22 n-tiles
                    int m_t = u / 22, nl = u - m_t * 22;
                    int n_t = x * 22 + nl;
                    int m0 = m_t * 16, n0 = n_t * 16;
                    f4 acc = {};
                    const ushort_t* brow = Wzc + (size_t)(n0 + lr) * KZ + quad * 8;
                    const ushort_t* drow = Dt + (size_t)(m0 + lr) * 64 + quad * 8;
                    #pragma unroll
                    for (int ks = 0; ks < 2; ++ks) {       // k 0..63: descriptors
                        sh8 a = *(const sh8*)(drow + ks * 32);
                        sh8 b = *(const sh8*)(brow + ks * 32);
                        acc = MFMA(a, b, acc);
                    }
                    const ushort_t* hrow = xn + (size_t)(m0 + lr) * 512 + 256 + quad * 8;
                    #pragma unroll
                    for (int ks = 0; ks < 8; ++ks) {       // k 64..319: h
                        sh8 a = *(const sh8*)(hrow + ks * 32);
                        sh8 b = *(const sh8*)(brow + 64 + ks * 32);
                        acc = MFMA(a, b, acc);
                    }
                    float bia = bfold[n0 + lr];
                    #pragma unroll
                    for (int r = 0; r < 4; ++r) {
                        float v = fmaxf(acc[r] + bia, 0.f);
                        z[(size_t)(m0 + quad * 4 + r) * CAT + n0 + lr] = f2bf(v);
                    }
                }
            }
        }
        gridbar(bars, bar++);

        // ================= Phase OF: out GEMM + fin =================
        {
            int m_t = -1, n_t = 0;
            if (bid < 128)      { m_t = bid >> 3; n_t = bid & 7; }
            else if (bid < 160) { int q = bid - 128; m_t = q >> 1; n_t = 8 + (q & 1); }
            if (m_t >= 0) {
                const int m0 = m_t * 32, n0 = n_t * 32;
                int k0, nk;
                if (w < 8) { k0 = w * 192; nk = 6; }                 // 8*192
                else       { k0 = 1536 + (w - 8) * 160; nk = 5; }    // + 8*160 = 2816
                f4 acc[2][2] = {};
                const ushort_t* za = z + (size_t)(m0 + lr) * CAT + k0 + quad * 8;
                const ushort_t* wb = Wout + (size_t)(n0 + lr) * CAT + k0 + quad * 8;
                for (int ks = 0; ks < nk; ++ks) {
                    sh8 a0 = *(const sh8*)(za + ks * 32);
                    sh8 a1 = *(const sh8*)(za + (size_t)16 * CAT + ks * 32);
                    sh8 b0 = *(const sh8*)(wb + ks * 32);
                    sh8 b1 = *(const sh8*)(wb + (size_t)16 * CAT + ks * 32);
                    acc[0][0] = MFMA(a0, b0, acc[0][0]);
                    acc[0][1] = MFMA(a0, b1, acc[0][1]);
                    acc[1][0] = MFMA(a1, b0, acc[1][0]);
                    acc[1][1] = MFMA(a1, b1, acc[1][1]);
                }
                if (w >= 8) {
                    #pragma unroll
                    for (int i = 0; i < 2; ++i)
                        #pragma unroll
                        for (int j2 = 0; j2 < 2; ++j2)
                            #pragma unroll
                            for (int r = 0; r < 4; ++r)
                                red[w - 8][i * 16 + quad * 4 + r][j2 * 16 + lr] = acc[i][j2][r];
                }
                __syncthreads();
                if (w < 8) {
                    #pragma unroll
                    for (int i = 0; i < 2; ++i)
                        #pragma unroll
                        for (int j2 = 0; j2 < 2; ++j2)
                            #pragma unroll
                            for (int r = 0; r < 4; ++r) {
                                float v = acc[i][j2][r] +
                                    red[w][i * 16 + quad * 4 + r][j2 * 16 + lr];
                                red[w][i * 16 + quad * 4 + r][j2 * 16 + lr] = v;
                            }
                }
                __syncthreads();
                {
                    int mloc = tid >> 5, nloc = tid & 31;
                    float s = 0.f;
                    #pragma unroll
                    for (int sI = 0; sI < 8; ++sI) s += red[sI][mloc][nloc];
                    int r = n0 + nloc, b = m0 + mloc;
                    if (r < 256) {
                        xn[(size_t)b * 512 + r] = f2bf(fmaxf(s + b2[r], 0.f));
                    } else if (r < NOUT) {
                        out[(size_t)b * (TT * NDD) + t * NDD + (r - 256)] = sigf(s + bv[r - 256]);
                    }
                }
            }
        }
        gridbar(bars, bar++);
    }
}

// ---------------------------------------------------------------------------
extern "C" void kernel_launch(void* const* d_in, const int* in_sizes, int n_in,
                              void* d_out, int out_size, void* d_ws, size_t ws_size,
                              hipStream_t stream)
{
    const float* desc = (const float*)d_in[0];
    const float* Wd   = (const float*)d_in[1];
    const float* bd   = (const float*)d_in[2];
    const float* W1   = (const float*)d_in[3];
    const float* b1   = (const float*)d_in[4];
    const float* W2   = (const float*)d_in[5];
    const float* b2   = (const float*)d_in[6];
    const float* Wv   = (const float*)d_in[7];
    const float* bv   = (const float*)d_in[8];
    const float* Wih  = (const float*)d_in[9];
    const float* Whh  = (const float*)d_in[10];
    const float* bih  = (const float*)d_in[11];
    const float* bhh  = (const float*)d_in[12];
    float* out = (float*)d_out;

    char* base = (char*)d_ws;
    size_t off = 0;
    auto alloc = [&](size_t bytes) -> char* {
        char* p = base + off;
        off = (off + bytes + 255) & ~(size_t)255;
        return p;
    };
    float*        c_    = (float*)alloc(BSZ * HID * 4);
    ushort_t*     xhA   = (ushort_t*)alloc(BSZ * 512 * 2);
    ushort_t*     xhB   = (ushort_t*)alloc(BSZ * 512 * 2);
    ushort_t*     z     = (ushort_t*)alloc((size_t)BSZ * CAT * 2);
    ushort_t*     Wzc   = (ushort_t*)alloc((size_t)CAT * KZ * 2);
    float*        bfold = (float*)alloc(CAT * 4);
    ushort_t*     Wg    = (ushort_t*)alloc(1024 * 512 * 2);
    float*        bg    = (float*)alloc(1024 * 4);
    ushort_t*     Wout  = (ushort_t*)alloc((size_t)NOUTP * CAT * 2);
    ushort_t*     Dfold = (ushort_t*)alloc((size_t)TT * BSZ * 64 * 2);
    unsigned int* bars  = (unsigned int*)alloc((TT * 3 + 4) * 4);

    hipMemsetAsync(c_,   0, BSZ * HID * 4, stream);
    hipMemsetAsync(xhA,  0, BSZ * 512 * 2, stream);
    hipMemsetAsync(bars, 0, (TT * 3 + 4) * 4, stream);

    k_fold  <<<CAT, 64, 0, stream>>>(W1, Wd, bd, b1, Wzc, bfold);
    k_dfold <<<(TT * BSZ * 64) / 256, 256, 0, stream>>>(desc, Dfold);
    k_prep_g<<<(1024 * 512) / 256, 256, 0, stream>>>(Wih, Whh, bih, bhh, Wg, bg);
    k_prep_o<<<(NOUTP * CAT) / 256, 256, 0, stream>>>(W2, Wv, Wout);

    void* args[] = {
        (void*)&Wg, (void*)&bg, (void*)&Wzc, (void*)&bfold, (void*)&Wout,
        (void*)&b2, (void*)&bv, (void*)&Dfold, (void*)&xhA, (void*)&xhB,
        (void*)&c_, (void*)&z, (void*)&out, (void*)&bars
    };
    hipLaunchCooperativeKernel((const void*)k_persist, dim3(NBLK), dim3(NTHR),
                               args, 0, stream);
}